// Round 2
// baseline (498.522 us; speedup 1.0000x reference)
//
#include <hip/hip_runtime.h>
#include <math.h>

using u16 = unsigned short;
typedef __attribute__((ext_vector_type(8))) short short8;
typedef __attribute__((ext_vector_type(4))) float floatx4;

constexpr int Bc = 32, Nn = 500, Mm = 500, Dd = 256;
constexpr int MP = 512;                 // padded M for ekT buffers (16B-aligned rows)
constexpr float LOGIT_CLIP = 10.0f;
constexpr float INV_SQRT_D = 1.0f / 16.0f;

__device__ __forceinline__ floatx4 mfma_bf16(short8 a, short8 b, floatx4 c) {
    return __builtin_amdgcn_mfma_f32_16x16x32_bf16(a, b, c, 0, 0, 0);
}

// split fp32 x into bf16 hi (RTN) + bf16 lo (RTN of residual): x ~= hi + lo
__device__ __forceinline__ void split1(float x, u16& h, u16& l) {
    unsigned u = __float_as_uint(x);
    unsigned rh = (u + 0x7FFFu + ((u >> 16) & 1u)) & 0xFFFF0000u;
    float fh = __uint_as_float(rh);
    float fl = x - fh;
    unsigned ul = __float_as_uint(fl);
    unsigned rl = ul + 0x7FFFu + ((ul >> 16) & 1u);
    h = (u16)(rh >> 16);
    l = (u16)(rl >> 16);
}

// ---------------------------------------------------------------------------
// K0: generic fp32 -> (bf16 hi, bf16 lo) splitter. blockIdx.y selects source.
// nper must be a multiple of 2048.
// ---------------------------------------------------------------------------
__global__ __launch_bounds__(256) void k0_split(const float* __restrict__ s0,
                                                const float* __restrict__ s1,
                                                const float* __restrict__ s2,
                                                const float* __restrict__ s3,
                                                u16* __restrict__ hb,
                                                u16* __restrict__ lb, int nper) {
    const float* s = blockIdx.y == 0 ? s0 : blockIdx.y == 1 ? s1 :
                     blockIdx.y == 2 ? s2 : s3;
    u16* h = hb + (size_t)blockIdx.y * nper;
    u16* l = lb + (size_t)blockIdx.y * nper;
    const int i = (blockIdx.x * 256 + threadIdx.x) * 8;
    if (i >= nper) return;
    float4 a = *(const float4*)&s[i];
    float4 c = *(const float4*)&s[i + 4];
    short8 hv, lv;
    u16 hh, ll;
    split1(a.x, hh, ll); hv[0] = (short)hh; lv[0] = (short)ll;
    split1(a.y, hh, ll); hv[1] = (short)hh; lv[1] = (short)ll;
    split1(a.z, hh, ll); hv[2] = (short)hh; lv[2] = (short)ll;
    split1(a.w, hh, ll); hv[3] = (short)hh; lv[3] = (short)ll;
    split1(c.x, hh, ll); hv[4] = (short)hh; lv[4] = (short)ll;
    split1(c.y, hh, ll); hv[5] = (short)hh; lv[5] = (short)ll;
    split1(c.z, hh, ll); hv[6] = (short)hh; lv[6] = (short)ll;
    split1(c.w, hh, ll); hv[7] = (short)hh; lv[7] = (short)ll;
    *(short8*)&h[i] = hv;
    *(short8*)&l[i] = lv;
}

// ---------------------------------------------------------------------------
// K1: ekT[b][d][m] = exp(k), ekvT = ek*v where k/v = jobs @ Wk^T / Wv^T.
// Transposed-output GEMM: C[d][m] = sum_t Wk[d][t] * jobs[m][t].
// A = W (rows d, contig t), B = jobs (cols m, contig t). Split-3 bf16 MFMA.
// grid (mtiles=8, dtiles=4, B), block 256 = 2x2 waves of 32d x 32m.
// ---------------------------------------------------------------------------
__global__ __launch_bounds__(256) void k1_kv(const u16* __restrict__ jobsH,
                                             const u16* __restrict__ jobsL,
                                             const u16* __restrict__ wH,
                                             const u16* __restrict__ wL,
                                             u16* __restrict__ ekTH, u16* __restrict__ ekTL,
                                             u16* __restrict__ ekvTH, u16* __restrict__ ekvTL) {
    const int lane = threadIdx.x & 63, wv = threadIdx.x >> 6;
    const int l16 = lane & 15, quad = lane >> 4;
    const int wd = wv >> 1, wm = wv & 1;
    const int b = blockIdx.z;
    const int M0 = blockIdx.x * 64 + wm * 32;
    const int D0 = blockIdx.y * 64 + wd * 32;
    const u16* WkH = wH;             // weight pack order: Wk, Wv, Wq0, Wq1
    const u16* WkL = wL;
    const u16* WvH = wH + 65536;
    const u16* WvL = wL + 65536;

    floatx4 ak[2][2] = {};
    floatx4 av[2][2] = {};
    const size_t jb = (size_t)b * Mm;

    for (int t = 0; t < Dd; t += 32) {
        short8 kh[2], kl[2], vh[2], vl[2];
#pragma unroll
        for (int rt = 0; rt < 2; ++rt) {
            const size_t o = (size_t)(D0 + rt * 16 + l16) * Dd + t + quad * 8;
            kh[rt] = *(const short8*)(WkH + o);
            kl[rt] = *(const short8*)(WkL + o);
            vh[rt] = *(const short8*)(WvH + o);
            vl[rt] = *(const short8*)(WvL + o);
        }
        short8 bh[2], bl[2];
#pragma unroll
        for (int ct = 0; ct < 2; ++ct) {
            int m = M0 + ct * 16 + l16;
            m = m < Mm ? m : Mm - 1;
            const size_t o = (jb + m) * Dd + t + quad * 8;
            bh[ct] = *(const short8*)(jobsH + o);
            bl[ct] = *(const short8*)(jobsL + o);
        }
#pragma unroll
        for (int rt = 0; rt < 2; ++rt)
#pragma unroll
            for (int ct = 0; ct < 2; ++ct) {
                ak[rt][ct] = mfma_bf16(kh[rt], bh[ct], ak[rt][ct]);
                ak[rt][ct] = mfma_bf16(kh[rt], bl[ct], ak[rt][ct]);
                ak[rt][ct] = mfma_bf16(kl[rt], bh[ct], ak[rt][ct]);
                av[rt][ct] = mfma_bf16(vh[rt], bh[ct], av[rt][ct]);
                av[rt][ct] = mfma_bf16(vh[rt], bl[ct], av[rt][ct]);
                av[rt][ct] = mfma_bf16(vl[rt], bh[ct], av[rt][ct]);
            }
    }

    const size_t eb = (size_t)b * Dd;
#pragma unroll
    for (int rt = 0; rt < 2; ++rt)
#pragma unroll
        for (int ct = 0; ct < 2; ++ct) {
            const int m = M0 + ct * 16 + l16;
            if (m >= Mm) continue;
#pragma unroll
            for (int r = 0; r < 4; ++r) {
                const int d = D0 + rt * 16 + quad * 4 + r;
                const float ek = expf(ak[rt][ct][r]);
                const float ev = ek * av[rt][ct][r];
                const size_t o = (eb + d) * MP + m;
                u16 h, l;
                split1(ek, h, l); ekTH[o] = h; ekTL[o] = l;
                split1(ev, h, l); ekvTH[o] = h; ekvTL[o] = l;
            }
        }
}

// ---------------------------------------------------------------------------
// K2: sq[b][n][d] = sigmoid(q0@Wq0^T + q1@Wq1^T). Split-3 bf16 MFMA.
// grid (dtiles=4, ntiles=8, B), block 2x2 waves of 32n x 32d.
// ---------------------------------------------------------------------------
__global__ __launch_bounds__(256) void k2_q(const u16* __restrict__ q0H, const u16* __restrict__ q0L,
                                            const u16* __restrict__ q1H, const u16* __restrict__ q1L,
                                            const u16* __restrict__ wH, const u16* __restrict__ wL,
                                            float* __restrict__ sq) {
    const int lane = threadIdx.x & 63, wv = threadIdx.x >> 6;
    const int l16 = lane & 15, quad = lane >> 4;
    const int wn = wv >> 1, wdt = wv & 1;
    const int b = blockIdx.z;
    const int N0 = blockIdx.y * 64 + wn * 32;
    const int D0 = blockIdx.x * 64 + wdt * 32;
    const u16* W0H = wH + 131072;  // Wq0
    const u16* W0L = wL + 131072;
    const u16* W1H = wH + 196608;  // Wq1
    const u16* W1L = wL + 196608;

    floatx4 acc[2][2] = {};
    const size_t qb = (size_t)b * Nn;

    for (int t = 0; t < Dd; t += 32) {
        short8 a0h[2], a0l[2], a1h[2], a1l[2];
#pragma unroll
        for (int rt = 0; rt < 2; ++rt) {
            int n = N0 + rt * 16 + l16;
            n = n < Nn ? n : Nn - 1;
            const size_t o = (qb + n) * Dd + t + quad * 8;
            a0h[rt] = *(const short8*)(q0H + o);
            a0l[rt] = *(const short8*)(q0L + o);
            a1h[rt] = *(const short8*)(q1H + o);
            a1l[rt] = *(const short8*)(q1L + o);
        }
        short8 b0h[2], b0l[2], b1h[2], b1l[2];
#pragma unroll
        for (int ct = 0; ct < 2; ++ct) {
            const size_t o = (size_t)(D0 + ct * 16 + l16) * Dd + t + quad * 8;
            b0h[ct] = *(const short8*)(W0H + o);
            b0l[ct] = *(const short8*)(W0L + o);
            b1h[ct] = *(const short8*)(W1H + o);
            b1l[ct] = *(const short8*)(W1L + o);
        }
#pragma unroll
        for (int rt = 0; rt < 2; ++rt)
#pragma unroll
            for (int ct = 0; ct < 2; ++ct) {
                acc[rt][ct] = mfma_bf16(a0h[rt], b0h[ct], acc[rt][ct]);
                acc[rt][ct] = mfma_bf16(a0h[rt], b0l[ct], acc[rt][ct]);
                acc[rt][ct] = mfma_bf16(a0l[rt], b0h[ct], acc[rt][ct]);
                acc[rt][ct] = mfma_bf16(a1h[rt], b1h[ct], acc[rt][ct]);
                acc[rt][ct] = mfma_bf16(a1h[rt], b1l[ct], acc[rt][ct]);
                acc[rt][ct] = mfma_bf16(a1l[rt], b1h[ct], acc[rt][ct]);
            }
    }

#pragma unroll
    for (int rt = 0; rt < 2; ++rt)
#pragma unroll
        for (int r = 0; r < 4; ++r) {
            const int n = N0 + rt * 16 + quad * 4 + r;
            if (n >= Nn) continue;
#pragma unroll
            for (int ct = 0; ct < 2; ++ct) {
                const int d = D0 + ct * 16 + l16;
                sq[(qb + n) * Dd + d] = 1.0f / (1.0f + expf(-acc[rt][ct][r]));
            }
        }
}

// ---------------------------------------------------------------------------
// K3: expb = exp(-a1*ls*cost + mask); num = expb@ekv, den = expb@ek (K = m);
//     aafm = sigmoid(q) * nan_to_num(num/den); store as bf16 hi/lo.
// A staged in LDS in MFMA A-layout ([kquad][n][8], 16B-aligned, 2-way banks).
// grid (dtiles=2 (128 wide), ntiles=8 (64 tall), B); 4 waves each 16n x 128d.
// ---------------------------------------------------------------------------
__global__ __launch_bounds__(256) void k3_aafm(const float* __restrict__ cost,
                                               const float* __restrict__ mask,
                                               const u16* __restrict__ ekTH, const u16* __restrict__ ekTL,
                                               const u16* __restrict__ ekvTH, const u16* __restrict__ ekvTL,
                                               const float* __restrict__ sq,
                                               u16* __restrict__ aafmH, u16* __restrict__ aafmL,
                                               const float* __restrict__ alpha1,
                                               const float* __restrict__ lsc) {
    __shared__ __align__(16) u16 ebh[4][64][8];
    __shared__ __align__(16) u16 ebl[4][64][8];
    const int tid = threadIdx.x;
    const int lane = tid & 63, wv = tid >> 6;
    const int l16 = lane & 15, quad = lane >> 4;
    const int b = blockIdx.z;
    const int N0 = blockIdx.y * 64;
    const int D0 = blockIdx.x * 128;
    const float a1ls = alpha1[0] * lsc[0];
    const size_t eb = (size_t)b * Dd;

    floatx4 an[8] = {};
    floatx4 ad[8] = {};

    const int fn = tid >> 2;                         // fill row 0..63
    const int fq = tid & 3;                          // fill k-quad 0..3
    const int fr = min(N0 + fn, Nn - 1);             // clamped cost row
    const size_t frow = ((size_t)b * Nn + fr) * Mm;

    for (int mc = 0; mc < MP; mc += 32) {
        // ---- cooperative fill of expb tile (hi/lo) ----
        {
            const int mg = mc + fq * 8;
            u16 h8[8], l8[8];
            if (mg + 7 < Mm) {
                const float4 c0 = *(const float4*)&cost[frow + mg];
                const float4 c1 = *(const float4*)&cost[frow + mg + 4];
                const float4 k0 = *(const float4*)&mask[frow + mg];
                const float4 k1 = *(const float4*)&mask[frow + mg + 4];
                float e[8];
                e[0] = expf(fmaf(-a1ls, c0.x, k0.x));
                e[1] = expf(fmaf(-a1ls, c0.y, k0.y));
                e[2] = expf(fmaf(-a1ls, c0.z, k0.z));
                e[3] = expf(fmaf(-a1ls, c0.w, k0.w));
                e[4] = expf(fmaf(-a1ls, c1.x, k1.x));
                e[5] = expf(fmaf(-a1ls, c1.y, k1.y));
                e[6] = expf(fmaf(-a1ls, c1.z, k1.z));
                e[7] = expf(fmaf(-a1ls, c1.w, k1.w));
#pragma unroll
                for (int j = 0; j < 8; ++j) split1(e[j], h8[j], l8[j]);
            } else {
#pragma unroll
                for (int j = 0; j < 8; ++j) {
                    const int m = mg + j;
                    float e = 0.0f;  // zero contribution beyond M (incl. padding)
                    if (m < Mm) e = expf(fmaf(-a1ls, cost[frow + m], mask[frow + m]));
                    split1(e, h8[j], l8[j]);
                }
            }
            short8 hv, lv;
#pragma unroll
            for (int j = 0; j < 8; ++j) { hv[j] = (short)h8[j]; lv[j] = (short)l8[j]; }
            *(short8*)&ebh[fq][fn][0] = hv;
            *(short8*)&ebl[fq][fn][0] = lv;
        }
        __syncthreads();

        const short8 ah = *(const short8*)&ebh[quad][wv * 16 + l16][0];
        const short8 al = *(const short8*)&ebl[quad][wv * 16 + l16][0];
#pragma unroll
        for (int ct = 0; ct < 8; ++ct) {
            const size_t o = (eb + D0 + ct * 16 + l16) * MP + mc + quad * 8;
            const short8 beh = *(const short8*)(ekTH + o);
            const short8 bel = *(const short8*)(ekTL + o);
            const short8 bvh = *(const short8*)(ekvTH + o);
            const short8 bvl = *(const short8*)(ekvTL + o);
            ad[ct] = mfma_bf16(ah, beh, ad[ct]);
            ad[ct] = mfma_bf16(ah, bel, ad[ct]);
            ad[ct] = mfma_bf16(al, beh, ad[ct]);
            an[ct] = mfma_bf16(ah, bvh, an[ct]);
            an[ct] = mfma_bf16(ah, bvl, an[ct]);
            an[ct] = mfma_bf16(al, bvh, an[ct]);
        }
        __syncthreads();
    }

#pragma unroll
    for (int r = 0; r < 4; ++r) {
        const int n = N0 + wv * 16 + quad * 4 + r;
        if (n >= Nn) continue;
        const size_t rowo = ((size_t)b * Nn + n) * Dd;
#pragma unroll
        for (int ct = 0; ct < 8; ++ct) {
            const int d = D0 + ct * 16 + l16;
            const float den = ad[ct][r];
            const float w = (den != 0.0f) ? an[ct][r] / den : 0.0f;
            const float a = sq[rowo + d] * w;
            u16 h, l;
            split1(a, h, l);
            aafmH[rowo + d] = h;
            aafmL[rowo + d] = l;
        }
    }
}

// ---------------------------------------------------------------------------
// K4: out = 10*tanh((aafm@jobs^T)/16 - a2*ls*cost) + mask (logits, pre-softmax)
// grid (mtiles=8, ntiles=8, B), block 2x2 waves of 32n x 32m.
// ---------------------------------------------------------------------------
__global__ __launch_bounds__(256) void k4_score(const u16* __restrict__ aafmH,
                                                const u16* __restrict__ aafmL,
                                                const u16* __restrict__ jobsH,
                                                const u16* __restrict__ jobsL,
                                                const float* __restrict__ cost,
                                                const float* __restrict__ mask,
                                                const float* __restrict__ alpha2,
                                                const float* __restrict__ lsc,
                                                float* __restrict__ out) {
    const int lane = threadIdx.x & 63, wv = threadIdx.x >> 6;
    const int l16 = lane & 15, quad = lane >> 4;
    const int wn = wv >> 1, wm = wv & 1;
    const int b = blockIdx.z;
    const int N0 = blockIdx.y * 64 + wn * 32;
    const int M0 = blockIdx.x * 64 + wm * 32;
    const float a2ls = alpha2[0] * lsc[0];
    const size_t rb = (size_t)b * Nn;

    floatx4 acc[2][2] = {};

    for (int t = 0; t < Dd; t += 32) {
        short8 ah[2], al[2];
#pragma unroll
        for (int rt = 0; rt < 2; ++rt) {
            int n = N0 + rt * 16 + l16;
            n = n < Nn ? n : Nn - 1;
            const size_t o = (rb + n) * Dd + t + quad * 8;
            ah[rt] = *(const short8*)(aafmH + o);
            al[rt] = *(const short8*)(aafmL + o);
        }
        short8 bh[2], bl[2];
#pragma unroll
        for (int ct = 0; ct < 2; ++ct) {
            int m = M0 + ct * 16 + l16;
            m = m < Mm ? m : Mm - 1;
            const size_t o = (rb + m) * Dd + t + quad * 8;
            bh[ct] = *(const short8*)(jobsH + o);
            bl[ct] = *(const short8*)(jobsL + o);
        }
#pragma unroll
        for (int rt = 0; rt < 2; ++rt)
#pragma unroll
            for (int ct = 0; ct < 2; ++ct) {
                acc[rt][ct] = mfma_bf16(ah[rt], bh[ct], acc[rt][ct]);
                acc[rt][ct] = mfma_bf16(ah[rt], bl[ct], acc[rt][ct]);
                acc[rt][ct] = mfma_bf16(al[rt], bh[ct], acc[rt][ct]);
            }
    }

    const size_t cb = (size_t)b * Nn * Mm;
#pragma unroll
    for (int ct = 0; ct < 2; ++ct) {
        const int m = M0 + ct * 16 + l16;
        if (m >= Mm) continue;
#pragma unroll
        for (int rt = 0; rt < 2; ++rt)
#pragma unroll
            for (int r = 0; r < 4; ++r) {
                const int n = N0 + rt * 16 + quad * 4 + r;
                if (n >= Nn) continue;
                const size_t o = cb + (size_t)n * Mm + m;
                const float s = fmaf(-a2ls, cost[o], acc[rt][ct][r] * INV_SQRT_D);
                out[o] = LOGIT_CLIP * tanhf(s) + mask[o];
            }
    }
}

// ---------------------------------------------------------------------------
// K5: in-place row softmax over M=500. One wave per row, 4 rows per block.
// ---------------------------------------------------------------------------
__global__ __launch_bounds__(256) void k5_softmax(float* __restrict__ out) {
    const int wave = threadIdx.x >> 6;
    const int lane = threadIdx.x & 63;
    const int row = blockIdx.x * 4 + wave;  // 4000 blocks -> 16000 rows
    float* p = out + (size_t)row * Mm;

    float4 v1 = *(const float4*)&p[lane << 2];
    const bool has2 = lane < 61;  // 125 float4 per row
    float4 v2 = {-1e30f, -1e30f, -1e30f, -1e30f};
    if (has2) v2 = *(const float4*)&p[(64 + lane) << 2];

    float mx = fmaxf(fmaxf(fmaxf(v1.x, v1.y), fmaxf(v1.z, v1.w)),
                     fmaxf(fmaxf(v2.x, v2.y), fmaxf(v2.z, v2.w)));
#pragma unroll
    for (int off = 32; off > 0; off >>= 1) mx = fmaxf(mx, __shfl_xor(mx, off));

    float4 e1, e2;
    e1.x = expf(v1.x - mx); e1.y = expf(v1.y - mx); e1.z = expf(v1.z - mx); e1.w = expf(v1.w - mx);
    e2.x = expf(v2.x - mx); e2.y = expf(v2.y - mx); e2.z = expf(v2.z - mx); e2.w = expf(v2.w - mx);
    float s = e1.x + e1.y + e1.z + e1.w + e2.x + e2.y + e2.z + e2.w;
#pragma unroll
    for (int off = 32; off > 0; off >>= 1) s += __shfl_xor(s, off);

    const float inv = 1.0f / s;
    e1.x *= inv; e1.y *= inv; e1.z *= inv; e1.w *= inv;
    *(float4*)&p[lane << 2] = e1;
    if (has2) {
        e2.x *= inv; e2.y *= inv; e2.z *= inv; e2.w *= inv;
        *(float4*)&p[(64 + lane) << 2] = e2;
    }
}

// ---------------------------------------------------------------------------
extern "C" void kernel_launch(void* const* d_in, const int* in_sizes, int n_in,
                              void* d_out, int out_size, void* d_ws, size_t ws_size,
                              hipStream_t stream) {
    const float* q0        = (const float*)d_in[0];
    const float* jobs      = (const float*)d_in[1];
    const float* q1        = (const float*)d_in[2];
    const float* cost      = (const float*)d_in[3];
    const float* log_scale = (const float*)d_in[4];
    const float* mask      = (const float*)d_in[5];
    const float* Wq0       = (const float*)d_in[6];
    const float* Wq1       = (const float*)d_in[7];
    const float* Wk        = (const float*)d_in[8];
    const float* Wv        = (const float*)d_in[9];
    const float* alpha1    = (const float*)d_in[10];
    const float* alpha2    = (const float*)d_in[11];
    float* out = (float*)d_out;

    const size_t NBD = (size_t)Bc * Nn * Dd;   // 4,096,000
    const size_t NTP = (size_t)Bc * Dd * MP;   // 4,194,304

    u16* ws    = (u16*)d_ws;
    u16* bigH  = ws;                 // [jobs | q0 | q1] hi
    u16* bigL  = bigH + 3 * NBD;     // [jobs | q0 | q1] lo
    u16* wH    = bigL + 3 * NBD;     // [Wk | Wv | Wq0 | Wq1] hi
    u16* wL    = wH + 4 * 65536;
    u16* ekTH  = wL + 4 * 65536;
    u16* ekTL  = ekTH + NTP;
    u16* ekvTH = ekTL + NTP;
    u16* ekvTL = ekvTH + NTP;
    float* sq  = (float*)(ekvTL + NTP);  // 4,096,000 fp32

    u16* jobsH = bigH;
    u16* jobsL = bigL;
    u16* q0H   = bigH + NBD;
    u16* q0L   = bigL + NBD;
    u16* q1H   = bigH + 2 * NBD;
    u16* q1L   = bigL + 2 * NBD;
    u16* aafmH = q0H;  // q0 splits dead after k2 -> alias
    u16* aafmL = q0L;

    dim3 blk(256);
    k0_split<<<dim3(32, 4), blk, 0, stream>>>(Wk, Wv, Wq0, Wq1, wH, wL, Dd * Dd);
    k0_split<<<dim3(2000, 3), blk, 0, stream>>>(jobs, q0, q1, jobs, bigH, bigL, (int)NBD);
    k1_kv<<<dim3(8, 4, 32), blk, 0, stream>>>(jobsH, jobsL, wH, wL, ekTH, ekTL, ekvTH, ekvTL);
    k2_q<<<dim3(4, 8, 32), blk, 0, stream>>>(q0H, q0L, q1H, q1L, wH, wL, sq);
    k3_aafm<<<dim3(2, 8, 32), blk, 0, stream>>>(cost, mask, ekTH, ekTL, ekvTH, ekvTL,
                                                sq, aafmH, aafmL, alpha1, log_scale);
    k4_score<<<dim3(8, 8, 32), blk, 0, stream>>>(aafmH, aafmL, jobsH, jobsL, cost, mask,
                                                 alpha2, log_scale, out);
    k5_softmax<<<4000, blk, 0, stream>>>(out);
}

// Round 3
// 406.148 us; speedup vs baseline: 1.2274x; 1.2274x over previous
//
#include <hip/hip_runtime.h>
#include <math.h>

using u16 = unsigned short;
typedef __attribute__((ext_vector_type(8))) short short8;
typedef __attribute__((ext_vector_type(16))) float floatx16;

constexpr int Bc = 32, Nn = 500, Mm = 500, Dd = 256, MP = 512;
constexpr float LOGIT_CLIP = 10.0f;
constexpr float INV_SQRT_D = 1.0f / 16.0f;

__device__ __forceinline__ floatx16 mfma32(short8 a, short8 b, floatx16 c) {
    return __builtin_amdgcn_mfma_f32_32x32x16_bf16(a, b, c, 0, 0, 0);
}

__device__ __forceinline__ floatx16 zero16() {
    floatx16 v = {0.f,0.f,0.f,0.f,0.f,0.f,0.f,0.f,0.f,0.f,0.f,0.f,0.f,0.f,0.f,0.f};
    return v;
}

// split fp32 x into bf16 hi (RTN) + bf16 lo (RTN of residual): x ~= hi + lo
__device__ __forceinline__ void split1(float x, u16& h, u16& l) {
    unsigned u = __float_as_uint(x);
    unsigned rh = (u + 0x7FFFu + ((u >> 16) & 1u)) & 0xFFFF0000u;
    float fh = __uint_as_float(rh);
    float fl = x - fh;
    unsigned ul = __float_as_uint(fl);
    unsigned rl = ul + 0x7FFFu + ((ul >> 16) & 1u);
    h = (u16)(rh >> 16);
    l = (u16)(rl >> 16);
}

__device__ __forceinline__ u16 bf16rtn(float x) {
    unsigned u = __float_as_uint(x);
    return (u16)((u + 0x7FFFu + ((u >> 16) & 1u)) >> 16);
}

__device__ __forceinline__ float fast_tanh(float x) {
    return 1.0f - 2.0f / (__expf(2.0f * x) + 1.0f);
}

// ---------------------------------------------------------------------------
// K0w: weights fp32 -> bf16 hi/lo, 4 sources packed [Wk|Wv|Wq0|Wq1]
// ---------------------------------------------------------------------------
__global__ __launch_bounds__(256) void k0w(const float* __restrict__ s0,
                                           const float* __restrict__ s1,
                                           const float* __restrict__ s2,
                                           const float* __restrict__ s3,
                                           u16* __restrict__ hb, u16* __restrict__ lb,
                                           int nper) {
    const float* s = blockIdx.y == 0 ? s0 : blockIdx.y == 1 ? s1 :
                     blockIdx.y == 2 ? s2 : s3;
    u16* h = hb + (size_t)blockIdx.y * nper;
    u16* l = lb + (size_t)blockIdx.y * nper;
    const int i = (blockIdx.x * 256 + threadIdx.x) * 8;
    if (i >= nper) return;
    float4 a = *(const float4*)&s[i];
    float4 c = *(const float4*)&s[i + 4];
    short8 hv, lv; u16 hh, ll;
    split1(a.x, hh, ll); hv[0] = (short)hh; lv[0] = (short)ll;
    split1(a.y, hh, ll); hv[1] = (short)hh; lv[1] = (short)ll;
    split1(a.z, hh, ll); hv[2] = (short)hh; lv[2] = (short)ll;
    split1(a.w, hh, ll); hv[3] = (short)hh; lv[3] = (short)ll;
    split1(c.x, hh, ll); hv[4] = (short)hh; lv[4] = (short)ll;
    split1(c.y, hh, ll); hv[5] = (short)hh; lv[5] = (short)ll;
    split1(c.z, hh, ll); hv[6] = (short)hh; lv[6] = (short)ll;
    split1(c.w, hh, ll); hv[7] = (short)hh; lv[7] = (short)ll;
    *(short8*)&h[i] = hv;
    *(short8*)&l[i] = lv;
}

// K0s: single-source fp32 -> bf16 hi/lo (n = 4,096,000 exact; 2000 blocks)
__global__ __launch_bounds__(256) void k0s(const float* __restrict__ s,
                                           u16* __restrict__ h, u16* __restrict__ l) {
    const int i = (blockIdx.x * 256 + threadIdx.x) * 8;
    float4 a = *(const float4*)&s[i];
    float4 c = *(const float4*)&s[i + 4];
    short8 hv, lv; u16 hh, ll;
    split1(a.x, hh, ll); hv[0] = (short)hh; lv[0] = (short)ll;
    split1(a.y, hh, ll); hv[1] = (short)hh; lv[1] = (short)ll;
    split1(a.z, hh, ll); hv[2] = (short)hh; lv[2] = (short)ll;
    split1(a.w, hh, ll); hv[3] = (short)hh; lv[3] = (short)ll;
    split1(c.x, hh, ll); hv[4] = (short)hh; lv[4] = (short)ll;
    split1(c.y, hh, ll); hv[5] = (short)hh; lv[5] = (short)ll;
    split1(c.z, hh, ll); hv[6] = (short)hh; lv[6] = (short)ll;
    split1(c.w, hh, ll); hv[7] = (short)hh; lv[7] = (short)ll;
    *(short8*)&h[i] = hv;
    *(short8*)&l[i] = lv;
}

// ---------------------------------------------------------------------------
// KEXP: expb[b][n][mp] = bf16( exp(-a1*ls*cost + mask) ), m-padded to 512 w/ 0
// ---------------------------------------------------------------------------
__global__ __launch_bounds__(256) void kexp(const float* __restrict__ cost,
                                            const float* __restrict__ mask,
                                            const float* __restrict__ alpha1,
                                            const float* __restrict__ lsc,
                                            u16* __restrict__ expbH) {
    const float a1ls = alpha1[0] * lsc[0];
    const int row = blockIdx.x * 2 + (threadIdx.x >> 7);  // 0..15999
    const int m0 = (threadIdx.x & 127) * 4;
    ushort4 w;
    if (m0 < Mm) {
        const size_t o = (size_t)row * Mm + m0;
        float4 cc = *(const float4*)&cost[o];
        float4 mm = *(const float4*)&mask[o];
        w.x = bf16rtn(__expf(fmaf(-a1ls, cc.x, mm.x)));
        w.y = bf16rtn(__expf(fmaf(-a1ls, cc.y, mm.y)));
        w.z = bf16rtn(__expf(fmaf(-a1ls, cc.z, mm.z)));
        w.w = bf16rtn(__expf(fmaf(-a1ls, cc.w, mm.w)));
    } else {
        w.x = 0; w.y = 0; w.z = 0; w.w = 0;
    }
    *(ushort4*)&expbH[(size_t)row * MP + m0] = w;
}

// ---------------------------------------------------------------------------
// K1: ekT[b][d][m]=exp(k), ekvT=ek*v; k/v = jobs@Wk^T/Wv^T; split-bf16 hi/lo out
// 32x32x16 MFMA. Block: 4 waves stacked on d (128d x 64m). grid (mt8, dt2, b32).
// ---------------------------------------------------------------------------
__global__ __launch_bounds__(256) void k1_kv(const u16* __restrict__ jobsH,
                                             const u16* __restrict__ jobsL,
                                             const u16* __restrict__ wH,
                                             const u16* __restrict__ wL,
                                             u16* __restrict__ ekTH, u16* __restrict__ ekTL,
                                             u16* __restrict__ ekvTH, u16* __restrict__ ekvTL) {
    const int lane = threadIdx.x & 63, wv = threadIdx.x >> 6;
    const int l31 = lane & 31, h = lane >> 5;
    const int b = blockIdx.z;
    const int D0 = blockIdx.y * 128 + wv * 32;
    const int M0 = blockIdx.x * 64;

    const size_t ar = (size_t)(D0 + l31) * Dd + h * 8;                  // Wk row; Wv = +65536
    const size_t jr0 = ((size_t)b * Mm + min(M0 + l31, Mm - 1)) * Dd + h * 8;
    const size_t jr1 = ((size_t)b * Mm + min(M0 + 32 + l31, Mm - 1)) * Dd + h * 8;

    floatx16 ak0 = zero16(), ak1 = zero16(), av0 = zero16(), av1 = zero16();

#pragma unroll
    for (int t = 0; t < Dd; t += 16) {
        short8 kh = *(const short8*)(wH + ar + t);
        short8 kl = *(const short8*)(wL + ar + t);
        short8 vh = *(const short8*)(wH + 65536 + ar + t);
        short8 vl = *(const short8*)(wL + 65536 + ar + t);
        short8 b0h = *(const short8*)(jobsH + jr0 + t);
        short8 b0l = *(const short8*)(jobsL + jr0 + t);
        short8 b1h = *(const short8*)(jobsH + jr1 + t);
        short8 b1l = *(const short8*)(jobsL + jr1 + t);
        ak0 = mfma32(kh, b0h, ak0); ak0 = mfma32(kh, b0l, ak0); ak0 = mfma32(kl, b0h, ak0);
        av0 = mfma32(vh, b0h, av0); av0 = mfma32(vh, b0l, av0); av0 = mfma32(vl, b0h, av0);
        ak1 = mfma32(kh, b1h, ak1); ak1 = mfma32(kh, b1l, ak1); ak1 = mfma32(kl, b1h, ak1);
        av1 = mfma32(vh, b1h, av1); av1 = mfma32(vh, b1l, av1); av1 = mfma32(vl, b1h, av1);
    }

#pragma unroll
    for (int r = 0; r < 16; ++r) {
        const int d = D0 + (r & 3) + ((r >> 2) << 3) + (h << 2);
        const size_t dbase = ((size_t)b * Dd + d) * MP;
        const int m0 = M0 + l31;
        {   // ct = 0 (m0 <= 63+.. always < 500 when M0<=448; guard anyway)
            if (m0 < Mm) {
                const float ek = __expf(ak0[r]);
                const float ev = ek * av0[r];
                u16 hh, ll;
                split1(ek, hh, ll); ekTH[dbase + m0] = hh; ekTL[dbase + m0] = ll;
                split1(ev, hh, ll); ekvTH[dbase + m0] = hh; ekvTL[dbase + m0] = ll;
            }
        }
        {   // ct = 1
            const int m1 = m0 + 32;
            if (m1 < Mm) {
                const float ek = __expf(ak1[r]);
                const float ev = ek * av1[r];
                u16 hh, ll;
                split1(ek, hh, ll); ekTH[dbase + m1] = hh; ekTL[dbase + m1] = ll;
                split1(ev, hh, ll); ekvTH[dbase + m1] = hh; ekvTL[dbase + m1] = ll;
            }
        }
    }
}

// ---------------------------------------------------------------------------
// K2: sq[b][n][d] = sigmoid(q0@Wq0^T + q1@Wq1^T), fp32 out.
// Block: 4 waves on n (128n x 64d). grid (dt4, nt4, b32).
// ---------------------------------------------------------------------------
__global__ __launch_bounds__(256) void k2_q(const u16* __restrict__ q0H, const u16* __restrict__ q0L,
                                            const u16* __restrict__ q1H, const u16* __restrict__ q1L,
                                            const u16* __restrict__ wH, const u16* __restrict__ wL,
                                            float* __restrict__ sq) {
    const int lane = threadIdx.x & 63, wv = threadIdx.x >> 6;
    const int l31 = lane & 31, h = lane >> 5;
    const int b = blockIdx.z;
    const int N0 = blockIdx.y * 128 + wv * 32;
    const int D0 = blockIdx.x * 64;

    const size_t ar  = ((size_t)b * Nn + min(N0 + l31, Nn - 1)) * Dd + h * 8;
    const size_t wr0 = (size_t)(D0 + l31) * Dd + h * 8;
    const size_t wr1 = (size_t)(D0 + 32 + l31) * Dd + h * 8;
    const u16* W0H = wH + 131072; const u16* W0L = wL + 131072;
    const u16* W1H = wH + 196608; const u16* W1L = wL + 196608;

    floatx16 acc0 = zero16(), acc1 = zero16();

#pragma unroll
    for (int t = 0; t < Dd; t += 16) {
        short8 a0h = *(const short8*)(q0H + ar + t);
        short8 a0l = *(const short8*)(q0L + ar + t);
        short8 a1h = *(const short8*)(q1H + ar + t);
        short8 a1l = *(const short8*)(q1L + ar + t);
        short8 b00h = *(const short8*)(W0H + wr0 + t);
        short8 b00l = *(const short8*)(W0L + wr0 + t);
        short8 b10h = *(const short8*)(W1H + wr0 + t);
        short8 b10l = *(const short8*)(W1L + wr0 + t);
        short8 b01h = *(const short8*)(W0H + wr1 + t);
        short8 b01l = *(const short8*)(W0L + wr1 + t);
        short8 b11h = *(const short8*)(W1H + wr1 + t);
        short8 b11l = *(const short8*)(W1L + wr1 + t);
        acc0 = mfma32(a0h, b00h, acc0); acc0 = mfma32(a0h, b00l, acc0); acc0 = mfma32(a0l, b00h, acc0);
        acc0 = mfma32(a1h, b10h, acc0); acc0 = mfma32(a1h, b10l, acc0); acc0 = mfma32(a1l, b10h, acc0);
        acc1 = mfma32(a0h, b01h, acc1); acc1 = mfma32(a0h, b01l, acc1); acc1 = mfma32(a0l, b01h, acc1);
        acc1 = mfma32(a1h, b11h, acc1); acc1 = mfma32(a1h, b11l, acc1); acc1 = mfma32(a1l, b11h, acc1);
    }

#pragma unroll
    for (int r = 0; r < 16; ++r) {
        const int n = N0 + (r & 3) + ((r >> 2) << 3) + (h << 2);
        if (n < Nn) {
            const size_t o = ((size_t)b * Nn + n) * Dd + D0 + l31;
            sq[o]      = 1.0f / (1.0f + __expf(-acc0[r]));
            sq[o + 32] = 1.0f / (1.0f + __expf(-acc1[r]));
        }
    }
}

// ---------------------------------------------------------------------------
// K3: num/den = expb @ (ekvT/ekT)^T over m (K=512 padded); aafm = sq*num/den.
// Block: 4 waves on d -> 32n x 256d full-D (no A redundancy, no LDS/barriers).
// Double-buffered register prefetch. Grid flat 512, b-colocating XCD swizzle.
// ---------------------------------------------------------------------------
__global__ __launch_bounds__(256) void k3_aafm(const u16* __restrict__ expbH,
                                               const u16* __restrict__ ekTH, const u16* __restrict__ ekTL,
                                               const u16* __restrict__ ekvTH, const u16* __restrict__ ekvTL,
                                               const float* __restrict__ sq,
                                               u16* __restrict__ aafmH, u16* __restrict__ aafmL) {
    const int i = blockIdx.x;
    const int x = i & 7, j = i >> 3;
    const int nt = j & 15;
    const int b = ((j >> 4) << 3) + x;      // all 16 nt of b land on XCD x (stride 8)
    const int lane = threadIdx.x & 63, wv = threadIdx.x >> 6;
    const int l31 = lane & 31, h = lane >> 5;
    const int N0 = nt << 5;
    const int Dw = wv << 6;

    const size_t arow = ((size_t)b * Nn + min(N0 + l31, Nn - 1)) * MP + h * 8;
    const size_t br0  = ((size_t)b * Dd + Dw + l31) * MP + h * 8;
    const size_t br1  = br0 + (size_t)32 * MP;

    floatx16 dn0 = zero16(), dn1 = zero16(), nm0 = zero16(), nm1 = zero16();

    short8 A0, e00, f00, g00, k00, e01, f01, g01, k01;   // set0: A, (ekH,ekL,evH,evL) x ct
    short8 A1, e10, f10, g10, k10, e11, f11, g11, k11;   // set1

#define K3LOAD(S, OFF) \
    A##S  = *(const short8*)(expbH + arow + (OFF)); \
    e##S##0 = *(const short8*)(ekTH  + br0 + (OFF)); \
    f##S##0 = *(const short8*)(ekTL  + br0 + (OFF)); \
    g##S##0 = *(const short8*)(ekvTH + br0 + (OFF)); \
    k##S##0 = *(const short8*)(ekvTL + br0 + (OFF)); \
    e##S##1 = *(const short8*)(ekTH  + br1 + (OFF)); \
    f##S##1 = *(const short8*)(ekTL  + br1 + (OFF)); \
    g##S##1 = *(const short8*)(ekvTH + br1 + (OFF)); \
    k##S##1 = *(const short8*)(ekvTL + br1 + (OFF));

#define K3MFMA(S) \
    dn0 = mfma32(A##S, e##S##0, dn0); dn0 = mfma32(A##S, f##S##0, dn0); \
    nm0 = mfma32(A##S, g##S##0, nm0); nm0 = mfma32(A##S, k##S##0, nm0); \
    dn1 = mfma32(A##S, e##S##1, dn1); dn1 = mfma32(A##S, f##S##1, dn1); \
    nm1 = mfma32(A##S, g##S##1, nm1); nm1 = mfma32(A##S, k##S##1, nm1);

    K3LOAD(0, 0)
#pragma unroll
    for (int mc = 0; mc < MP; mc += 32) {
        K3LOAD(1, mc + 16)
        K3MFMA(0)
        if (mc + 32 < MP) { K3LOAD(0, mc + 32) }
        K3MFMA(1)
    }
#undef K3LOAD
#undef K3MFMA

#pragma unroll
    for (int r = 0; r < 16; ++r) {
        const int n = N0 + (r & 3) + ((r >> 2) << 3) + (h << 2);
        if (n < Nn) {
            const size_t o0 = ((size_t)b * Nn + n) * Dd + Dw + l31;
            u16 hh, ll;
            const float d0 = dn0[r];
            const float w0 = (d0 != 0.f) ? nm0[r] / d0 : 0.f;
            split1(sq[o0] * w0, hh, ll); aafmH[o0] = hh; aafmL[o0] = ll;
            const size_t o1 = o0 + 32;
            const float d1 = dn1[r];
            const float w1 = (d1 != 0.f) ? nm1[r] / d1 : 0.f;
            split1(sq[o1] * w1, hh, ll); aafmH[o1] = hh; aafmL[o1] = ll;
        }
    }
}

// ---------------------------------------------------------------------------
// K4: logits = 10*tanh((aafm@jobs^T)/16 - a2*ls*cost) + mask, FUSED row softmax.
// Block 512 thr = 8 waves; each wave 32n x 64m; block covers 32n x 512m (all m).
// Grid flat 512, b-colocating swizzle. LDS cross-wave max/sum reduce.
// ---------------------------------------------------------------------------
__global__ __launch_bounds__(512) void k4_score(const u16* __restrict__ aafmH,
                                                const u16* __restrict__ aafmL,
                                                const u16* __restrict__ jobsH,
                                                const u16* __restrict__ jobsL,
                                                const float* __restrict__ cost,
                                                const float* __restrict__ mask,
                                                const float* __restrict__ alpha2,
                                                const float* __restrict__ lsc,
                                                float* __restrict__ out) {
    __shared__ float pred[32][8];
    const int i = blockIdx.x;
    const int x = i & 7, j = i >> 3;
    const int nt = j & 15;
    const int b = ((j >> 4) << 3) + x;
    const int lane = threadIdx.x & 63, wv = threadIdx.x >> 6;  // wv 0..7
    const int l31 = lane & 31, h = lane >> 5;
    const int N0 = nt << 5;
    const float a2ls = alpha2[0] * lsc[0];

    const size_t arow = ((size_t)b * Nn + min(N0 + l31, Nn - 1)) * Dd + h * 8;
    const int m0g = wv * 64 + l31;           // < 512; ct0 cols (<480, always valid)
    const int m1g = m0g + 32;                // can exceed 499
    const size_t br0 = ((size_t)b * Mm + min(m0g, Mm - 1)) * Dd + h * 8;
    const size_t br1 = ((size_t)b * Mm + min(m1g, Mm - 1)) * Dd + h * 8;

    floatx16 acc0 = zero16(), acc1 = zero16();
    short8 P0, Q0, r00, s00, r01, s01;
    short8 P1, Q1, r10, s10, r11, s11;

#define K4LOAD(S, OFF) \
    P##S = *(const short8*)(aafmH + arow + (OFF)); \
    Q##S = *(const short8*)(aafmL + arow + (OFF)); \
    r##S##0 = *(const short8*)(jobsH + br0 + (OFF)); \
    s##S##0 = *(const short8*)(jobsL + br0 + (OFF)); \
    r##S##1 = *(const short8*)(jobsH + br1 + (OFF)); \
    s##S##1 = *(const short8*)(jobsL + br1 + (OFF));

#define K4MFMA(S) \
    acc0 = mfma32(P##S, r##S##0, acc0); acc0 = mfma32(P##S, s##S##0, acc0); acc0 = mfma32(Q##S, r##S##0, acc0); \
    acc1 = mfma32(P##S, r##S##1, acc1); acc1 = mfma32(P##S, s##S##1, acc1); acc1 = mfma32(Q##S, r##S##1, acc1);

    K4LOAD(0, 0)
#pragma unroll
    for (int t = 0; t < Dd; t += 32) {
        K4LOAD(1, t + 16)
        K4MFMA(0)
        if (t + 32 < Dd) { K4LOAD(0, t + 32) }
        K4MFMA(1)
    }
#undef K4LOAD
#undef K4MFMA

    // ---- epilogue: logits ----
    float lg0[16], lg1[16];
    const size_t cb = (size_t)b * Nn * Mm;
#pragma unroll
    for (int r = 0; r < 16; ++r) {
        const int row = (r & 3) + ((r >> 2) << 3) + (h << 2);
        const int n = N0 + row;
        if (n < Nn) {
            const size_t o = cb + (size_t)n * Mm + m0g;
            lg0[r] = LOGIT_CLIP * fast_tanh(fmaf(-a2ls, cost[o], acc0[r] * INV_SQRT_D)) + mask[o];
            if (m1g < Mm) {
                const size_t o1 = o + 32;
                lg1[r] = LOGIT_CLIP * fast_tanh(fmaf(-a2ls, cost[o1], acc1[r] * INV_SQRT_D)) + mask[o1];
            } else lg1[r] = -1e30f;
        } else { lg0[r] = -1e30f; lg1[r] = -1e30f; }
    }

    // ---- row max: butterfly within 32-lane half, then cross-wave via LDS ----
    float rm[16];
#pragma unroll
    for (int r = 0; r < 16; ++r) rm[r] = fmaxf(lg0[r], lg1[r]);
#pragma unroll
    for (int d = 1; d < 32; d <<= 1)
#pragma unroll
        for (int r = 0; r < 16; ++r) rm[r] = fmaxf(rm[r], __shfl_xor(rm[r], d));
    if (l31 == 0) {
#pragma unroll
        for (int r = 0; r < 16; ++r)
            pred[(r & 3) + ((r >> 2) << 3) + (h << 2)][wv] = rm[r];
    }
    __syncthreads();
    float fm[16];
#pragma unroll
    for (int r = 0; r < 16; ++r) {
        const int row = (r & 3) + ((r >> 2) << 3) + (h << 2);
        float v = pred[row][0];
#pragma unroll
        for (int w = 1; w < 8; ++w) v = fmaxf(v, pred[row][w]);
        fm[r] = v;
    }
    __syncthreads();

    // ---- exp + row sum ----
    float sm[16];
#pragma unroll
    for (int r = 0; r < 16; ++r) {
        lg0[r] = __expf(lg0[r] - fm[r]);
        lg1[r] = __expf(lg1[r] - fm[r]);
        sm[r] = lg0[r] + lg1[r];
    }
#pragma unroll
    for (int d = 1; d < 32; d <<= 1)
#pragma unroll
        for (int r = 0; r < 16; ++r) sm[r] += __shfl_xor(sm[r], d);
    if (l31 == 0) {
#pragma unroll
        for (int r = 0; r < 16; ++r)
            pred[(r & 3) + ((r >> 2) << 3) + (h << 2)][wv] = sm[r];
    }
    __syncthreads();

    // ---- normalize + store ----
#pragma unroll
    for (int r = 0; r < 16; ++r) {
        const int row = (r & 3) + ((r >> 2) << 3) + (h << 2);
        const int n = N0 + row;
        if (n < Nn) {
            float s = pred[row][0];
#pragma unroll
            for (int w = 1; w < 8; ++w) s += pred[row][w];
            const float inv = 1.0f / s;
            const size_t o = cb + (size_t)n * Mm + m0g;
            out[o] = lg0[r] * inv;
            if (m1g < Mm) out[o + 32] = lg1[r] * inv;
        }
    }
}

// ---------------------------------------------------------------------------
extern "C" void kernel_launch(void* const* d_in, const int* in_sizes, int n_in,
                              void* d_out, int out_size, void* d_ws, size_t ws_size,
                              hipStream_t stream) {
    const float* q0        = (const float*)d_in[0];
    const float* jobs      = (const float*)d_in[1];
    const float* q1        = (const float*)d_in[2];
    const float* cost      = (const float*)d_in[3];
    const float* log_scale = (const float*)d_in[4];
    const float* mask      = (const float*)d_in[5];
    const float* Wq0       = (const float*)d_in[6];
    const float* Wq1       = (const float*)d_in[7];
    const float* Wk        = (const float*)d_in[8];
    const float* Wv        = (const float*)d_in[9];
    const float* alpha1    = (const float*)d_in[10];
    const float* alpha2    = (const float*)d_in[11];
    float* out = (float*)d_out;

    const size_t NBD = (size_t)Bc * Nn * Dd;   // 4,096,000
    const size_t BTP = (size_t)Bc * Dd * MP;   // 4,194,304

    u16* ws    = (u16*)d_ws;
    u16* jobsH = ws;                 // [jobsH | q0H | q1H | q1L | q0L | jobsL]
    u16* q0H   = ws + NBD;
    u16* q1H   = ws + 2 * NBD;       // } expbH aliases q1H..q1L (2*NBD = 32*500*512 exact)
    u16* q1L   = ws + 3 * NBD;
    u16* q0L   = ws + 4 * NBD;
    u16* jobsL = ws + 5 * NBD;
    u16* wH    = ws + 6 * NBD;       // [Wk|Wv|Wq0|Wq1] hi
    u16* wL    = wH + 4 * 65536;
    u16* ekTH  = wL + 4 * 65536;
    u16* ekTL  = ekTH + BTP;
    u16* ekvTH = ekTL + BTP;
    u16* ekvTL = ekvTH + BTP;
    float* sq  = (float*)(ekvTL + BTP);  // 4,096,000 fp32

    u16* expbH = q1H;   // valid after k2 (q1 splits dead)
    u16* aafmH = q0H;   // valid after k2 (q0 splits dead)
    u16* aafmL = q0L;

    dim3 blk(256);
    k0w<<<dim3(32, 4), blk, 0, stream>>>(Wk, Wv, Wq0, Wq1, wH, wL, Dd * Dd);
    k0s<<<2000, blk, 0, stream>>>(jobs, jobsH, jobsL);
    k0s<<<2000, blk, 0, stream>>>(q0, q0H, q0L);
    k0s<<<2000, blk, 0, stream>>>(q1, q1H, q1L);
    k1_kv<<<dim3(8, 2, 32), blk, 0, stream>>>(jobsH, jobsL, wH, wL, ekTH, ekTL, ekvTH, ekvTL);
    k2_q<<<dim3(4, 4, 32), blk, 0, stream>>>(q0H, q0L, q1H, q1L, wH, wL, sq);
    kexp<<<8000, blk, 0, stream>>>(cost, mask, alpha1, log_scale, expbH);
    k3_aafm<<<512, blk, 0, stream>>>(expbH, ekTH, ekTL, ekvTH, ekvTL, sq, aafmH, aafmL);
    k4_score<<<512, dim3(512), 0, stream>>>(aafmH, aafmL, jobsH, jobsL, cost, mask,
                                            alpha2, log_scale, out);
}

// Round 4
// 400.488 us; speedup vs baseline: 1.2448x; 1.0141x over previous
//
#include <hip/hip_runtime.h>
#include <math.h>

using u16 = unsigned short;
typedef __attribute__((ext_vector_type(8))) short short8;
typedef __attribute__((ext_vector_type(16))) float floatx16;

constexpr int Bc = 32, Nn = 500, Mm = 500, Dd = 256, MP = 512;
constexpr float LOGIT_CLIP = 10.0f;
constexpr float INV_SQRT_D = 1.0f / 16.0f;

__device__ __forceinline__ floatx16 mfma32(short8 a, short8 b, floatx16 c) {
    return __builtin_amdgcn_mfma_f32_32x32x16_bf16(a, b, c, 0, 0, 0);
}

__device__ __forceinline__ floatx16 zero16() {
    floatx16 v = {0.f,0.f,0.f,0.f,0.f,0.f,0.f,0.f,0.f,0.f,0.f,0.f,0.f,0.f,0.f,0.f};
    return v;
}

// split fp32 x into bf16 hi (RTN) + bf16 lo (RTN of residual): x ~= hi + lo
__device__ __forceinline__ void split1(float x, u16& h, u16& l) {
    unsigned u = __float_as_uint(x);
    unsigned rh = (u + 0x7FFFu + ((u >> 16) & 1u)) & 0xFFFF0000u;
    float fh = __uint_as_float(rh);
    float fl = x - fh;
    unsigned ul = __float_as_uint(fl);
    unsigned rl = ul + 0x7FFFu + ((ul >> 16) & 1u);
    h = (u16)(rh >> 16);
    l = (u16)(rl >> 16);
}

__device__ __forceinline__ u16 bf16rtn(float x) {
    unsigned u = __float_as_uint(x);
    return (u16)((u + 0x7FFFu + ((u >> 16) & 1u)) >> 16);
}

__device__ __forceinline__ float fast_tanh(float x) {
    return 1.0f - 2.0f / (__expf(2.0f * x) + 1.0f);
}

// ---------------------------------------------------------------------------
// K0w: weights fp32 -> bf16 hi/lo, 4 sources packed [Wk|Wv|Wq0|Wq1]
// ---------------------------------------------------------------------------
__global__ __launch_bounds__(256) void k0w(const float* __restrict__ s0,
                                           const float* __restrict__ s1,
                                           const float* __restrict__ s2,
                                           const float* __restrict__ s3,
                                           u16* __restrict__ hb, u16* __restrict__ lb,
                                           int nper) {
    const float* s = blockIdx.y == 0 ? s0 : blockIdx.y == 1 ? s1 :
                     blockIdx.y == 2 ? s2 : s3;
    u16* h = hb + (size_t)blockIdx.y * nper;
    u16* l = lb + (size_t)blockIdx.y * nper;
    const int i = (blockIdx.x * 256 + threadIdx.x) * 8;
    if (i >= nper) return;
    float4 a = *(const float4*)&s[i];
    float4 c = *(const float4*)&s[i + 4];
    short8 hv, lv; u16 hh, ll;
    split1(a.x, hh, ll); hv[0] = (short)hh; lv[0] = (short)ll;
    split1(a.y, hh, ll); hv[1] = (short)hh; lv[1] = (short)ll;
    split1(a.z, hh, ll); hv[2] = (short)hh; lv[2] = (short)ll;
    split1(a.w, hh, ll); hv[3] = (short)hh; lv[3] = (short)ll;
    split1(c.x, hh, ll); hv[4] = (short)hh; lv[4] = (short)ll;
    split1(c.y, hh, ll); hv[5] = (short)hh; lv[5] = (short)ll;
    split1(c.z, hh, ll); hv[6] = (short)hh; lv[6] = (short)ll;
    split1(c.w, hh, ll); hv[7] = (short)hh; lv[7] = (short)ll;
    *(short8*)&h[i] = hv;
    *(short8*)&l[i] = lv;
}

// K0s3: three sources (jobs,q0,q1) -> contiguous hi/lo regions, blockIdx.y picks
__global__ __launch_bounds__(256) void k0s3(const float* __restrict__ s0,
                                            const float* __restrict__ s1,
                                            const float* __restrict__ s2,
                                            u16* __restrict__ h0, u16* __restrict__ l0,
                                            u16* __restrict__ h1, u16* __restrict__ l1,
                                            u16* __restrict__ h2, u16* __restrict__ l2) {
    const float* s = blockIdx.y == 0 ? s0 : blockIdx.y == 1 ? s1 : s2;
    u16* h = blockIdx.y == 0 ? h0 : blockIdx.y == 1 ? h1 : h2;
    u16* l = blockIdx.y == 0 ? l0 : blockIdx.y == 1 ? l1 : l2;
    const int i = (blockIdx.x * 256 + threadIdx.x) * 8;
    float4 a = *(const float4*)&s[i];
    float4 c = *(const float4*)&s[i + 4];
    short8 hv, lv; u16 hh, ll;
    split1(a.x, hh, ll); hv[0] = (short)hh; lv[0] = (short)ll;
    split1(a.y, hh, ll); hv[1] = (short)hh; lv[1] = (short)ll;
    split1(a.z, hh, ll); hv[2] = (short)hh; lv[2] = (short)ll;
    split1(a.w, hh, ll); hv[3] = (short)hh; lv[3] = (short)ll;
    split1(c.x, hh, ll); hv[4] = (short)hh; lv[4] = (short)ll;
    split1(c.y, hh, ll); hv[5] = (short)hh; lv[5] = (short)ll;
    split1(c.z, hh, ll); hv[6] = (short)hh; lv[6] = (short)ll;
    split1(c.w, hh, ll); hv[7] = (short)hh; lv[7] = (short)ll;
    *(short8*)&h[i] = hv;
    *(short8*)&l[i] = lv;
}

// ---------------------------------------------------------------------------
// KEXP: expb[b][n][mp] = bf16( exp(-a1*ls*cost + mask) ), m-padded to 512 w/ 0
// ---------------------------------------------------------------------------
__global__ __launch_bounds__(256) void kexp(const float* __restrict__ cost,
                                            const float* __restrict__ mask,
                                            const float* __restrict__ alpha1,
                                            const float* __restrict__ lsc,
                                            u16* __restrict__ expbH) {
    const float a1ls = alpha1[0] * lsc[0];
    const int row = blockIdx.x * 2 + (threadIdx.x >> 7);  // 0..15999
    const int m0 = (threadIdx.x & 127) * 4;
    ushort4 w;
    if (m0 < Mm) {
        const size_t o = (size_t)row * Mm + m0;
        float4 cc = *(const float4*)&cost[o];
        float4 mm = *(const float4*)&mask[o];
        w.x = bf16rtn(__expf(fmaf(-a1ls, cc.x, mm.x)));
        w.y = bf16rtn(__expf(fmaf(-a1ls, cc.y, mm.y)));
        w.z = bf16rtn(__expf(fmaf(-a1ls, cc.z, mm.z)));
        w.w = bf16rtn(__expf(fmaf(-a1ls, cc.w, mm.w)));
    } else {
        w.x = 0; w.y = 0; w.z = 0; w.w = 0;
    }
    *(ushort4*)&expbH[(size_t)row * MP + m0] = w;
}

// ---------------------------------------------------------------------------
// K1: ekT[b][d][m]=exp(k), ekvT=ek*v; k/v = jobs@Wk^T/Wv^T; split-bf16 hi/lo out
// 32x32x16 MFMA. Depth-2 (3-set) register prefetch pipeline.
// ---------------------------------------------------------------------------
__global__ __launch_bounds__(256) void k1_kv(const u16* __restrict__ jobsH,
                                             const u16* __restrict__ jobsL,
                                             const u16* __restrict__ wH,
                                             const u16* __restrict__ wL,
                                             u16* __restrict__ ekTH, u16* __restrict__ ekTL,
                                             u16* __restrict__ ekvTH, u16* __restrict__ ekvTL) {
    const int lane = threadIdx.x & 63, wv = threadIdx.x >> 6;
    const int l31 = lane & 31, h = lane >> 5;
    const int b = blockIdx.z;
    const int D0 = blockIdx.y * 128 + wv * 32;
    const int M0 = blockIdx.x * 64;

    const size_t ar = (size_t)(D0 + l31) * Dd + h * 8;
    const size_t jr0 = ((size_t)b * Mm + min(M0 + l31, Mm - 1)) * Dd + h * 8;
    const size_t jr1 = ((size_t)b * Mm + min(M0 + 32 + l31, Mm - 1)) * Dd + h * 8;

    floatx16 ak0 = zero16(), ak1 = zero16(), av0 = zero16(), av1 = zero16();

    short8 buf[3][8];
#define K1L(S, OFF) { \
    buf[S][0] = *(const short8*)(wH + ar + (OFF)); \
    buf[S][1] = *(const short8*)(wL + ar + (OFF)); \
    buf[S][2] = *(const short8*)(wH + 65536 + ar + (OFF)); \
    buf[S][3] = *(const short8*)(wL + 65536 + ar + (OFF)); \
    buf[S][4] = *(const short8*)(jobsH + jr0 + (OFF)); \
    buf[S][5] = *(const short8*)(jobsL + jr0 + (OFF)); \
    buf[S][6] = *(const short8*)(jobsH + jr1 + (OFF)); \
    buf[S][7] = *(const short8*)(jobsL + jr1 + (OFF)); }

    K1L(0, 0)
    K1L(1, 16)
#pragma unroll
    for (int it = 0; it < 16; ++it) {
        if (it + 2 < 16) { K1L((it + 2) % 3, (it + 2) * 16) }
        const int c = it % 3;
        ak0 = mfma32(buf[c][0], buf[c][4], ak0);
        ak0 = mfma32(buf[c][0], buf[c][5], ak0);
        ak0 = mfma32(buf[c][1], buf[c][4], ak0);
        av0 = mfma32(buf[c][2], buf[c][4], av0);
        av0 = mfma32(buf[c][2], buf[c][5], av0);
        av0 = mfma32(buf[c][3], buf[c][4], av0);
        ak1 = mfma32(buf[c][0], buf[c][6], ak1);
        ak1 = mfma32(buf[c][0], buf[c][7], ak1);
        ak1 = mfma32(buf[c][1], buf[c][6], ak1);
        av1 = mfma32(buf[c][2], buf[c][6], av1);
        av1 = mfma32(buf[c][2], buf[c][7], av1);
        av1 = mfma32(buf[c][3], buf[c][6], av1);
    }
#undef K1L

#pragma unroll
    for (int r = 0; r < 16; ++r) {
        const int d = D0 + (r & 3) + ((r >> 2) << 3) + (h << 2);
        const size_t dbase = ((size_t)b * Dd + d) * MP;
        const int m0 = M0 + l31;
        if (m0 < Mm) {
            const float ek = __expf(ak0[r]);
            const float ev = ek * av0[r];
            u16 hh, ll;
            split1(ek, hh, ll); ekTH[dbase + m0] = hh; ekTL[dbase + m0] = ll;
            split1(ev, hh, ll); ekvTH[dbase + m0] = hh; ekvTL[dbase + m0] = ll;
        }
        const int m1 = m0 + 32;
        if (m1 < Mm) {
            const float ek = __expf(ak1[r]);
            const float ev = ek * av1[r];
            u16 hh, ll;
            split1(ek, hh, ll); ekTH[dbase + m1] = hh; ekTL[dbase + m1] = ll;
            split1(ev, hh, ll); ekvTH[dbase + m1] = hh; ekvTL[dbase + m1] = ll;
        }
    }
}

// ---------------------------------------------------------------------------
// K2: sq[b][n][d] = sigmoid(q0@Wq0^T + q1@Wq1^T), fp32 out. 3-set pipeline.
// ---------------------------------------------------------------------------
__global__ __launch_bounds__(256) void k2_q(const u16* __restrict__ q0H, const u16* __restrict__ q0L,
                                            const u16* __restrict__ q1H, const u16* __restrict__ q1L,
                                            const u16* __restrict__ wH, const u16* __restrict__ wL,
                                            float* __restrict__ sq) {
    const int lane = threadIdx.x & 63, wv = threadIdx.x >> 6;
    const int l31 = lane & 31, h = lane >> 5;
    const int b = blockIdx.z;
    const int N0 = blockIdx.y * 128 + wv * 32;
    const int D0 = blockIdx.x * 64;

    const size_t ar  = ((size_t)b * Nn + min(N0 + l31, Nn - 1)) * Dd + h * 8;
    const size_t wr0 = (size_t)(D0 + l31) * Dd + h * 8;
    const size_t wr1 = (size_t)(D0 + 32 + l31) * Dd + h * 8;
    const u16* W0H = wH + 131072; const u16* W0L = wL + 131072;
    const u16* W1H = wH + 196608; const u16* W1L = wL + 196608;

    floatx16 acc0 = zero16(), acc1 = zero16();

    short8 buf[3][12];
#define K2L(S, OFF) { \
    buf[S][0]  = *(const short8*)(q0H + ar + (OFF)); \
    buf[S][1]  = *(const short8*)(q0L + ar + (OFF)); \
    buf[S][2]  = *(const short8*)(q1H + ar + (OFF)); \
    buf[S][3]  = *(const short8*)(q1L + ar + (OFF)); \
    buf[S][4]  = *(const short8*)(W0H + wr0 + (OFF)); \
    buf[S][5]  = *(const short8*)(W0L + wr0 + (OFF)); \
    buf[S][6]  = *(const short8*)(W1H + wr0 + (OFF)); \
    buf[S][7]  = *(const short8*)(W1L + wr0 + (OFF)); \
    buf[S][8]  = *(const short8*)(W0H + wr1 + (OFF)); \
    buf[S][9]  = *(const short8*)(W0L + wr1 + (OFF)); \
    buf[S][10] = *(const short8*)(W1H + wr1 + (OFF)); \
    buf[S][11] = *(const short8*)(W1L + wr1 + (OFF)); }

    K2L(0, 0)
    K2L(1, 16)
#pragma unroll
    for (int it = 0; it < 16; ++it) {
        if (it + 2 < 16) { K2L((it + 2) % 3, (it + 2) * 16) }
        const int c = it % 3;
        acc0 = mfma32(buf[c][0], buf[c][4], acc0);
        acc0 = mfma32(buf[c][0], buf[c][5], acc0);
        acc0 = mfma32(buf[c][1], buf[c][4], acc0);
        acc0 = mfma32(buf[c][2], buf[c][6], acc0);
        acc0 = mfma32(buf[c][2], buf[c][7], acc0);
        acc0 = mfma32(buf[c][3], buf[c][6], acc0);
        acc1 = mfma32(buf[c][0], buf[c][8], acc1);
        acc1 = mfma32(buf[c][0], buf[c][9], acc1);
        acc1 = mfma32(buf[c][1], buf[c][8], acc1);
        acc1 = mfma32(buf[c][2], buf[c][10], acc1);
        acc1 = mfma32(buf[c][2], buf[c][11], acc1);
        acc1 = mfma32(buf[c][3], buf[c][10], acc1);
    }
#undef K2L

#pragma unroll
    for (int r = 0; r < 16; ++r) {
        const int n = N0 + (r & 3) + ((r >> 2) << 3) + (h << 2);
        if (n < Nn) {
            const size_t o = ((size_t)b * Nn + n) * Dd + D0 + l31;
            sq[o]      = 1.0f / (1.0f + __expf(-acc0[r]));
            sq[o + 32] = 1.0f / (1.0f + __expf(-acc1[r]));
        }
    }
}

// ---------------------------------------------------------------------------
// K3: num/den = expb @ (ekvT/ekT)^T over m (K=512 padded); aafm = sq*num/den.
// 32n x 256d per block (4 waves on d). 3-set register prefetch pipeline.
// Grid flat 512, b-colocating XCD swizzle.
// ---------------------------------------------------------------------------
__global__ __launch_bounds__(256) void k3_aafm(const u16* __restrict__ expbH,
                                               const u16* __restrict__ ekTH, const u16* __restrict__ ekTL,
                                               const u16* __restrict__ ekvTH, const u16* __restrict__ ekvTL,
                                               const float* __restrict__ sq,
                                               u16* __restrict__ aafmH, u16* __restrict__ aafmL) {
    const int i = blockIdx.x;
    const int x = i & 7, j = i >> 3;
    const int nt = j & 15;
    const int b = ((j >> 4) << 3) + x;      // all 16 nt of b land on XCD x (stride 8)
    const int lane = threadIdx.x & 63, wv = threadIdx.x >> 6;
    const int l31 = lane & 31, h = lane >> 5;
    const int N0 = nt << 5;
    const int Dw = wv << 6;

    const size_t arow = ((size_t)b * Nn + min(N0 + l31, Nn - 1)) * MP + h * 8;
    const size_t br0  = ((size_t)b * Dd + Dw + l31) * MP + h * 8;
    const size_t br1  = br0 + (size_t)32 * MP;

    floatx16 dn0 = zero16(), dn1 = zero16(), nm0 = zero16(), nm1 = zero16();

    short8 buf[3][9];
#define K3L(S, OFF) { \
    buf[S][0] = *(const short8*)(expbH + arow + (OFF)); \
    buf[S][1] = *(const short8*)(ekTH  + br0 + (OFF)); \
    buf[S][2] = *(const short8*)(ekTL  + br0 + (OFF)); \
    buf[S][3] = *(const short8*)(ekvTH + br0 + (OFF)); \
    buf[S][4] = *(const short8*)(ekvTL + br0 + (OFF)); \
    buf[S][5] = *(const short8*)(ekTH  + br1 + (OFF)); \
    buf[S][6] = *(const short8*)(ekTL  + br1 + (OFF)); \
    buf[S][7] = *(const short8*)(ekvTH + br1 + (OFF)); \
    buf[S][8] = *(const short8*)(ekvTL + br1 + (OFF)); }

    K3L(0, 0)
    K3L(1, 16)
#pragma unroll
    for (int it = 0; it < 32; ++it) {
        if (it + 2 < 32) { K3L((it + 2) % 3, (it + 2) * 16) }
        const int c = it % 3;
        dn0 = mfma32(buf[c][0], buf[c][1], dn0);
        dn0 = mfma32(buf[c][0], buf[c][2], dn0);
        nm0 = mfma32(buf[c][0], buf[c][3], nm0);
        nm0 = mfma32(buf[c][0], buf[c][4], nm0);
        dn1 = mfma32(buf[c][0], buf[c][5], dn1);
        dn1 = mfma32(buf[c][0], buf[c][6], dn1);
        nm1 = mfma32(buf[c][0], buf[c][7], nm1);
        nm1 = mfma32(buf[c][0], buf[c][8], nm1);
    }
#undef K3L

#pragma unroll
    for (int r = 0; r < 16; ++r) {
        const int n = N0 + (r & 3) + ((r >> 2) << 3) + (h << 2);
        if (n < Nn) {
            const size_t o0 = ((size_t)b * Nn + n) * Dd + Dw + l31;
            u16 hh, ll;
            const float d0 = dn0[r];
            const float w0 = (d0 != 0.f) ? nm0[r] / d0 : 0.f;
            split1(sq[o0] * w0, hh, ll); aafmH[o0] = hh; aafmL[o0] = ll;
            const size_t o1 = o0 + 32;
            const float d1 = dn1[r];
            const float w1 = (d1 != 0.f) ? nm1[r] / d1 : 0.f;
            split1(sq[o1] * w1, hh, ll); aafmH[o1] = hh; aafmL[o1] = ll;
        }
    }
}

// ---------------------------------------------------------------------------
// K4: logits = 10*tanh((aafm@jobs^T)/16 - a2*ls*cost) + mask, FUSED row softmax.
// Block 512 thr = 8 waves; each wave 32n x 64m; block covers 32n x 512m.
// 3-set register prefetch pipeline in the K(d)-loop.
// ---------------------------------------------------------------------------
__global__ __launch_bounds__(512) void k4_score(const u16* __restrict__ aafmH,
                                                const u16* __restrict__ aafmL,
                                                const u16* __restrict__ jobsH,
                                                const u16* __restrict__ jobsL,
                                                const float* __restrict__ cost,
                                                const float* __restrict__ mask,
                                                const float* __restrict__ alpha2,
                                                const float* __restrict__ lsc,
                                                float* __restrict__ out) {
    __shared__ float pred[32][8];
    const int i = blockIdx.x;
    const int x = i & 7, j = i >> 3;
    const int nt = j & 15;
    const int b = ((j >> 4) << 3) + x;
    const int lane = threadIdx.x & 63, wv = threadIdx.x >> 6;  // wv 0..7
    const int l31 = lane & 31, h = lane >> 5;
    const int N0 = nt << 5;
    const float a2ls = alpha2[0] * lsc[0];

    const size_t arow = ((size_t)b * Nn + min(N0 + l31, Nn - 1)) * Dd + h * 8;
    const int m0g = wv * 64 + l31;
    const int m1g = m0g + 32;
    const size_t br0 = ((size_t)b * Mm + min(m0g, Mm - 1)) * Dd + h * 8;
    const size_t br1 = ((size_t)b * Mm + min(m1g, Mm - 1)) * Dd + h * 8;

    floatx16 acc0 = zero16(), acc1 = zero16();

    short8 buf[3][6];
#define K4L(S, OFF) { \
    buf[S][0] = *(const short8*)(aafmH + arow + (OFF)); \
    buf[S][1] = *(const short8*)(aafmL + arow + (OFF)); \
    buf[S][2] = *(const short8*)(jobsH + br0 + (OFF)); \
    buf[S][3] = *(const short8*)(jobsL + br0 + (OFF)); \
    buf[S][4] = *(const short8*)(jobsH + br1 + (OFF)); \
    buf[S][5] = *(const short8*)(jobsL + br1 + (OFF)); }

    K4L(0, 0)
    K4L(1, 16)
#pragma unroll
    for (int it = 0; it < 16; ++it) {
        if (it + 2 < 16) { K4L((it + 2) % 3, (it + 2) * 16) }
        const int c = it % 3;
        acc0 = mfma32(buf[c][0], buf[c][2], acc0);
        acc0 = mfma32(buf[c][0], buf[c][3], acc0);
        acc0 = mfma32(buf[c][1], buf[c][2], acc0);
        acc1 = mfma32(buf[c][0], buf[c][4], acc1);
        acc1 = mfma32(buf[c][0], buf[c][5], acc1);
        acc1 = mfma32(buf[c][1], buf[c][4], acc1);
    }
#undef K4L

    // ---- epilogue: logits ----
    float lg0[16], lg1[16];
    const size_t cb = (size_t)b * Nn * Mm;
#pragma unroll
    for (int r = 0; r < 16; ++r) {
        const int row = (r & 3) + ((r >> 2) << 3) + (h << 2);
        const int n = N0 + row;
        if (n < Nn) {
            const size_t o = cb + (size_t)n * Mm + m0g;
            lg0[r] = LOGIT_CLIP * fast_tanh(fmaf(-a2ls, cost[o], acc0[r] * INV_SQRT_D)) + mask[o];
            if (m1g < Mm) {
                const size_t o1 = o + 32;
                lg1[r] = LOGIT_CLIP * fast_tanh(fmaf(-a2ls, cost[o1], acc1[r] * INV_SQRT_D)) + mask[o1];
            } else lg1[r] = -1e30f;
        } else { lg0[r] = -1e30f; lg1[r] = -1e30f; }
    }

    // ---- row max: butterfly within 32-lane half, then cross-wave via LDS ----
    float rm[16];
#pragma unroll
    for (int r = 0; r < 16; ++r) rm[r] = fmaxf(lg0[r], lg1[r]);
#pragma unroll
    for (int d = 1; d < 32; d <<= 1)
#pragma unroll
        for (int r = 0; r < 16; ++r) rm[r] = fmaxf(rm[r], __shfl_xor(rm[r], d));
    if (l31 == 0) {
#pragma unroll
        for (int r = 0; r < 16; ++r)
            pred[(r & 3) + ((r >> 2) << 3) + (h << 2)][wv] = rm[r];
    }
    __syncthreads();
    float fm[16];
#pragma unroll
    for (int r = 0; r < 16; ++r) {
        const int row = (r & 3) + ((r >> 2) << 3) + (h << 2);
        float v = pred[row][0];
#pragma unroll
        for (int w = 1; w < 8; ++w) v = fmaxf(v, pred[row][w]);
        fm[r] = v;
    }
    __syncthreads();

    // ---- exp + row sum ----
    float sm[16];
#pragma unroll
    for (int r = 0; r < 16; ++r) {
        lg0[r] = __expf(lg0[r] - fm[r]);
        lg1[r] = __expf(lg1[r] - fm[r]);
        sm[r] = lg0[r] + lg1[r];
    }
#pragma unroll
    for (int d = 1; d < 32; d <<= 1)
#pragma unroll
        for (int r = 0; r < 16; ++r) sm[r] += __shfl_xor(sm[r], d);
    if (l31 == 0) {
#pragma unroll
        for (int r = 0; r < 16; ++r)
            pred[(r & 3) + ((r >> 2) << 3) + (h << 2)][wv] = sm[r];
    }
    __syncthreads();

    // ---- normalize + store ----
#pragma unroll
    for (int r = 0; r < 16; ++r) {
        const int row = (r & 3) + ((r >> 2) << 3) + (h << 2);
        const int n = N0 + row;
        if (n < Nn) {
            float s = pred[row][0];
#pragma unroll
            for (int w = 1; w < 8; ++w) s += pred[row][w];
            const float inv = 1.0f / s;
            const size_t o = cb + (size_t)n * Mm + m0g;
            out[o] = lg0[r] * inv;
            if (m1g < Mm) out[o + 32] = lg1[r] * inv;
        }
    }
}

// ---------------------------------------------------------------------------
extern "C" void kernel_launch(void* const* d_in, const int* in_sizes, int n_in,
                              void* d_out, int out_size, void* d_ws, size_t ws_size,
                              hipStream_t stream) {
    const float* q0        = (const float*)d_in[0];
    const float* jobs      = (const float*)d_in[1];
    const float* q1        = (const float*)d_in[2];
    const float* cost      = (const float*)d_in[3];
    const float* log_scale = (const float*)d_in[4];
    const float* mask      = (const float*)d_in[5];
    const float* Wq0       = (const float*)d_in[6];
    const float* Wq1       = (const float*)d_in[7];
    const float* Wk        = (const float*)d_in[8];
    const float* Wv        = (const float*)d_in[9];
    const float* alpha1    = (const float*)d_in[10];
    const float* alpha2    = (const float*)d_in[11];
    float* out = (float*)d_out;

    const size_t NBD = (size_t)Bc * Nn * Dd;   // 4,096,000
    const size_t BTP = (size_t)Bc * Dd * MP;   // 4,194,304

    u16* ws    = (u16*)d_ws;
    u16* jobsH = ws;                 // [jobsH | q0H | q1H | q1L | q0L | jobsL]
    u16* q0H   = ws + NBD;
    u16* q1H   = ws + 2 * NBD;       // } expbH aliases q1H..q1L (2*NBD exact)
    u16* q1L   = ws + 3 * NBD;
    u16* q0L   = ws + 4 * NBD;
    u16* jobsL = ws + 5 * NBD;
    u16* wH    = ws + 6 * NBD;       // [Wk|Wv|Wq0|Wq1] hi
    u16* wL    = wH + 4 * 65536;
    u16* ekTH  = wL + 4 * 65536;
    u16* ekTL  = ekTH + BTP;
    u16* ekvTH = ekTL + BTP;
    u16* ekvTL = ekvTH + BTP;
    float* sq  = (float*)(ekvTL + BTP);  // 4,096,000 fp32

    u16* expbH = q1H;   // valid after k2 (q1 splits dead)
    u16* aafmH = q0H;   // valid after k2 (q0 splits dead)
    u16* aafmL = q0L;

    dim3 blk(256);
    k0w<<<dim3(32, 4), blk, 0, stream>>>(Wk, Wv, Wq0, Wq1, wH, wL, Dd * Dd);
    k0s3<<<dim3(2000, 3), blk, 0, stream>>>(jobs, q0, q1, jobsH, jobsL, q0H, q0L, q1H, q1L);
    k1_kv<<<dim3(8, 2, 32), blk, 0, stream>>>(jobsH, jobsL, wH, wL, ekTH, ekTL, ekvTH, ekvTL);
    k2_q<<<dim3(4, 4, 32), blk, 0, stream>>>(q0H, q0L, q1H, q1L, wH, wL, sq);
    kexp<<<8000, blk, 0, stream>>>(cost, mask, alpha1, log_scale, expbH);
    k3_aafm<<<512, blk, 0, stream>>>(expbH, ekTH, ekTL, ekvTH, ekvTL, sq, aafmH, aafmL);
    k4_score<<<512, dim3(512), 0, stream>>>(aafmH, aafmL, jobsH, jobsL, cost, mask,
                                            alpha2, log_scale, out);
}